// Round 6
// baseline (231.004 us; speedup 1.0000x reference)
//
#include <hip/hip_runtime.h>
#include <hip/hip_bf16.h>

#define EPSF 1e-8f
#define NN 50000
#define DD 128
#define BB 64
#define LL 512
#define PP0 200000
#define PP1 50000
#define SCALE 0.08838834764831845f  // 1/sqrt(128)

typedef float f4v __attribute__((ext_vector_type(4)));
typedef short s8v __attribute__((ext_vector_type(8)));
typedef short s4v __attribute__((ext_vector_type(4)));

__device__ __forceinline__ float logsigf(float x) {
    float s = 1.f / (1.f + __expf(-x));
    return __logf(s + EPSF);
}

__device__ __forceinline__ float red64(float v) {
    #pragma unroll
    for (int m = 32; m >= 1; m >>= 1) v += __shfl_xor(v, m, 64);
    return v;
}
__device__ __forceinline__ float red16(float v) {
    #pragma unroll
    for (int m = 8; m >= 1; m >>= 1) v += __shfl_xor(v, m, 64);
    return v;
}

__device__ __forceinline__ void block_atomic_sum(float local, float* dst) {
    local = red64(local);
    __shared__ float w4[4];
    if ((threadIdx.x & 63) == 0) w4[threadIdx.x >> 6] = local;
    __syncthreads();
    if (threadIdx.x == 0) atomicAdd(dst, w4[0] + w4[1] + w4[2] + w4[3]);
}

// float -> bf16 bits (round-to-nearest-even)
__device__ __forceinline__ unsigned short f2bf(float f) {
    unsigned u = __float_as_uint(f);
    unsigned r = (u + 0x7fffu + ((u >> 16) & 1u)) >> 16;
    return (unsigned short)r;
}
__device__ __forceinline__ float bf2f(unsigned short u) {
    return __uint_as_float(((unsigned)u) << 16);
}

__device__ __forceinline__ float dot8bf(s8v a, s8v b) {
    float s = 0.f;
    #pragma unroll
    for (int j = 0; j < 8; j++)
        s += bf2f((unsigned short)a[j]) * bf2f((unsigned short)b[j]);
    return s;
}

// ---------------- one-shot converts -----------------------------------------
__global__ __launch_bounds__(256) void cvt_emb_kernel(
    const float* __restrict__ emb, unsigned short* __restrict__ emb16)
{
    int stride = gridDim.x * 256 * 8;
    for (int i = (blockIdx.x * 256 + threadIdx.x) * 8; i < NN * DD; i += stride) {
        float4 a = *(const float4*)&emb[i];
        float4 b = *(const float4*)&emb[i + 4];
        s8v o;
        o[0] = (short)f2bf(a.x); o[1] = (short)f2bf(a.y);
        o[2] = (short)f2bf(a.z); o[3] = (short)f2bf(a.w);
        o[4] = (short)f2bf(b.x); o[5] = (short)f2bf(b.y);
        o[6] = (short)f2bf(b.z); o[7] = (short)f2bf(b.w);
        *(s8v*)&emb16[i] = o;
    }
}

__global__ __launch_bounds__(256) void cvt_w_kernel(
    const float* __restrict__ Wq, const float* __restrict__ Wk,
    const float* __restrict__ Wv, const float* __restrict__ Hd,
    unsigned short* __restrict__ W16)
{
    int idx = (blockIdx.x * 256 + threadIdx.x) * 8;
    int which = idx >> 14, off = idx & 16383;
    const float* src = (which == 0) ? Wq : (which == 1) ? Wk : (which == 2) ? Wv : Hd;
    float4 a = *(const float4*)&src[off];
    float4 b = *(const float4*)&src[off + 4];
    s8v o;
    o[0] = (short)f2bf(a.x); o[1] = (short)f2bf(a.y);
    o[2] = (short)f2bf(a.z); o[3] = (short)f2bf(a.w);
    o[4] = (short)f2bf(b.x); o[5] = (short)f2bf(b.y);
    o[6] = (short)f2bf(b.z); o[7] = (short)f2bf(b.w);
    *(s8v*)&W16[idx] = o;
}

// ---------------- Edge tasks, balanced grid-stride, 2x unrolled e0 ----------
// Every block runs e0-pos, e0-neg, e1 slices -> uniform per-block work.
#define ENB 2048
__global__ __launch_bounds__(256) void edges_kernel(
    const unsigned short* __restrict__ emb16, const int* __restrict__ pos,
    const int* __restrict__ neg, const int* __restrict__ pos1,
    const int* __restrict__ neg1, float* __restrict__ acc)
{
    int sub = threadIdx.x & 15;
    int g0 = blockIdx.x * 16 + (threadIdx.x >> 4);
    const int ng = ENB * 16;   // 32768 groups

    // ---- edge0 positive, unroll x2 for MLP ----
    float l0 = 0.f;
    for (int grp = g0; grp < PP0; grp += 2 * ng) {
        int h0 = pos[2 * grp], t0 = pos[2 * grp + 1];
        s8v a0 = *(const s8v*)&emb16[(size_t)h0 * DD + 8 * sub];
        s8v b0 = *(const s8v*)&emb16[(size_t)t0 * DD + 8 * sub];
        int grp1 = grp + ng;
        bool has2 = grp1 < PP0;
        s8v a1 = a0, b1 = b0;
        if (has2) {
            int h1 = pos[2 * grp1], t1 = pos[2 * grp1 + 1];
            a1 = *(const s8v*)&emb16[(size_t)h1 * DD + 8 * sub];
            b1 = *(const s8v*)&emb16[(size_t)t1 * DD + 8 * sub];
        }
        float d0 = red16(dot8bf(a0, b0));
        float d1 = red16(dot8bf(a1, b1));
        if (sub == 0) {
            l0 += logsigf(d0);
            if (has2) l0 += logsigf(d1);
        }
    }
    // ---- edge0 negative, unroll x2 ----
    for (int grp = g0; grp < PP0; grp += 2 * ng) {
        int h0 = neg[2 * grp], t0 = neg[2 * grp + 1];
        s8v a0 = *(const s8v*)&emb16[(size_t)h0 * DD + 8 * sub];
        s8v b0 = *(const s8v*)&emb16[(size_t)t0 * DD + 8 * sub];
        int grp1 = grp + ng;
        bool has2 = grp1 < PP0;
        s8v a1 = a0, b1 = b0;
        if (has2) {
            int h1 = neg[2 * grp1], t1 = neg[2 * grp1 + 1];
            a1 = *(const s8v*)&emb16[(size_t)h1 * DD + 8 * sub];
            b1 = *(const s8v*)&emb16[(size_t)t1 * DD + 8 * sub];
        }
        float d0 = red16(dot8bf(a0, b0));
        float d1 = red16(dot8bf(a1, b1));
        if (sub == 0) {
            l0 += logsigf(-d0);
            if (has2) l0 += logsigf(-d1);
        }
    }
    block_atomic_sum(l0, acc);

    // ---- edge1: pos pair reused x4, 10 gathers/iter (good native ILP) ----
    float l1 = 0.f;
    for (int i = g0; i < PP1; i += ng) {
        int ph = pos1[2 * i], pt = pos1[2 * i + 1];
        s8v vph = *(const s8v*)&emb16[(size_t)ph * DD + 8 * sub];
        s8v vpt = *(const s8v*)&emb16[(size_t)pt * DD + 8 * sub];
        float ps = red16(dot8bf(vph, vpt));
        #pragma unroll
        for (int mloop = 0; mloop < 4; mloop++) {
            int g = mloop * PP1 + i;
            int nh = neg1[2 * g], nt = neg1[2 * g + 1];
            s8v vnh = *(const s8v*)&emb16[(size_t)nh * DD + 8 * sub];
            s8v vnt = *(const s8v*)&emb16[(size_t)nt * DD + 8 * sub];
            float sh = red16(dot8bf(vnh, vpt));
            float st = red16(dot8bf(vph, vnt));
            if (sub == 0) l1 += logsigf(ps - sh) + logsigf(ps - st);
        }
    }
    block_atomic_sum(l1, acc + 1);
}

// ---------------- QKV projection, bf16 MFMA ---------------------------------
// Q,K row-major [b*L+t][d]; V written TRANSPOSED: VT16T[b][d=0..127][key=0..511]
__global__ __launch_bounds__(256) void proj_kernel(
    const unsigned short* __restrict__ emb16, const float* __restrict__ Wrep,
    const unsigned short* __restrict__ W16, const int* __restrict__ qseq,
    const int* __restrict__ cseq, unsigned short* __restrict__ QT16,
    unsigned short* __restrict__ KT16, unsigned short* __restrict__ VT16T)
{
    int b = blockIdx.y;
    int t0 = blockIdx.x * 64;
    __shared__ unsigned short Itok[64 * 136];
    __shared__ unsigned short Wl[128 * 136];   // reused as V^T[r][t] stride 72 in epilogue
    __shared__ int qs[64];
    __shared__ int cs[64];
    int tid = threadIdx.x;
    if (tid < 64) {
        qs[tid] = qseq[b * LL + t0 + tid];
        cs[tid] = cseq[b * LL + t0 + tid];
    }
    __syncthreads();
    {   // stage I[t][d] = emb[qs[t]][d] + Wrep[d][cs[t]] as bf16
        int t = tid >> 2, d0 = (tid & 3) * 32;
        const unsigned short* er = emb16 + (size_t)qs[t] * DD + d0;
        int c = cs[t];
        #pragma unroll
        for (int e = 0; e < 32; e += 8) {
            s8v raw = *(const s8v*)&er[e];
            s8v o;
            #pragma unroll
            for (int j = 0; j < 8; j++) {
                float f = bf2f((unsigned short)raw[j]) + Wrep[(d0 + e + j) * 2 + c];
                o[j] = (short)f2bf(f);
            }
            *(s8v*)&Itok[t * 136 + d0 + e] = o;
        }
    }
    int w = tid >> 6, lane = tid & 63, n = lane & 15, quad = lane >> 4;

    for (int w3 = 0; w3 < 3; w3++) {
        __syncthreads();
        {   // stage W[w3]
            const unsigned short* src = W16 + w3 * DD * DD + (tid >> 1) * DD + (tid & 1) * 64;
            unsigned short* dst = &Wl[(tid >> 1) * 136 + (tid & 1) * 64];
            #pragma unroll
            for (int e = 0; e < 64; e += 8)
                *(s8v*)&dst[e] = *(const s8v*)&src[e];
        }
        __syncthreads();
        f4v a2[2][4];
        #pragma unroll
        for (int mt = 0; mt < 2; mt++)
            #pragma unroll
            for (int nt = 0; nt < 4; nt++) a2[mt][nt] = (f4v){0.f, 0.f, 0.f, 0.f};
        #pragma unroll
        for (int c = 0; c < 4; c++) {
            s8v af0 = *(const s8v*)&Wl[(w * 32 + n) * 136 + c * 32 + quad * 8];
            s8v af1 = *(const s8v*)&Wl[(w * 32 + 16 + n) * 136 + c * 32 + quad * 8];
            #pragma unroll
            for (int nt = 0; nt < 4; nt++) {
                s8v bf = *(const s8v*)&Itok[(nt * 16 + n) * 136 + c * 32 + quad * 8];
                a2[0][nt] = __builtin_amdgcn_mfma_f32_16x16x32_bf16(af0, bf, a2[0][nt], 0, 0, 0);
                a2[1][nt] = __builtin_amdgcn_mfma_f32_16x16x32_bf16(af1, bf, a2[1][nt], 0, 0, 0);
            }
        }
        if (w3 < 2) {
            unsigned short* OUT = (w3 == 0) ? QT16 : KT16;
            #pragma unroll
            for (int mt = 0; mt < 2; mt++)
                #pragma unroll
                for (int nt = 0; nt < 4; nt++) {
                    int t = t0 + nt * 16 + n;
                    int r = w * 32 + mt * 16 + quad * 4;
                    s4v o;
                    #pragma unroll
                    for (int rr = 0; rr < 4; rr++) o[rr] = (short)f2bf(a2[mt][nt][rr]);
                    *(s4v*)&OUT[((size_t)(b * LL) + t) * DD + r] = o;
                }
        } else {
            // V: scatter into LDS [r][t] stride 72, then coalesced b128 store
            __syncthreads();   // all waves done reading Wl
            #pragma unroll
            for (int mt = 0; mt < 2; mt++)
                #pragma unroll
                for (int nt = 0; nt < 4; nt++) {
                    int tl = nt * 16 + n;
                    int r = w * 32 + mt * 16 + quad * 4;
                    #pragma unroll
                    for (int rr = 0; rr < 4; rr++)
                        Wl[(r + rr) * 72 + tl] = f2bf(a2[mt][nt][rr]);
                }
            __syncthreads();
            int row = tid >> 1, half = tid & 1;
            unsigned short* gdst = VT16T + ((size_t)b * DD + row) * LL + t0 + half * 32;
            const unsigned short* lsrc = &Wl[row * 72 + half * 32];
            #pragma unroll
            for (int e = 0; e < 32; e += 8)
                *(s8v*)&gdst[e] = *(const s8v*)&lsrc[e];
        }
    }
}

// ---------------- Flash attention, bf16 MFMA, pipelined staging -------------
__global__ __launch_bounds__(256) void attn_mfma_kernel(
    const unsigned short* __restrict__ QT16, const unsigned short* __restrict__ KT16,
    const unsigned short* __restrict__ VT16T, float* __restrict__ BvT)
{
    int id = blockIdx.x;
    int r0 = id & 255;
    int b = r0 & 63;
    int qt = (id >> 8) ? (7 - (r0 >> 6)) : (r0 >> 6);

    __shared__ unsigned short K_lds[64 * 136];   // [key][d]
    __shared__ unsigned short Vt_lds[128 * 72];  // [d][key]
    __shared__ unsigned short P_lds[64 * 72];    // [query][key]

    int tid = threadIdx.x;
    int w = tid >> 6;
    int lane = tid & 63;
    int n = lane & 15;
    int quad = lane >> 4;
    int gj = qt * 64 + w * 16 + n;

    s8v qfrag[4];
    {
        const unsigned short* qrow = QT16 + ((size_t)(b * LL) + gj) * DD;
        #pragma unroll
        for (int c = 0; c < 4; c++)
            qfrag[c] = *(const s8v*)&qrow[c * 32 + quad * 8];
    }

    f4v oacc[8];
    #pragma unroll
    for (int dt = 0; dt < 8; dt++) oacc[dt] = (f4v){0.f, 0.f, 0.f, 0.f};
    float m_run = -INFINITY, l_run = 0.f;

    s8v kreg[4], vreg[4];
    #pragma unroll
    for (int rep = 0; rep < 4; rep++) {
        int idx = rep * 2048 + tid * 8;
        int ki = idx >> 7, kd = idx & 127;
        kreg[rep] = *(const s8v*)&KT16[((size_t)(b * LL) + ki) * DD + kd];
        int vr = idx >> 6, vc = idx & 63;
        vreg[rep] = *(const s8v*)&VT16T[((size_t)b * DD + vr) * LL + vc];
    }

    for (int kt = 0; kt <= qt; ++kt) {
        __syncthreads();
        #pragma unroll
        for (int rep = 0; rep < 4; rep++) {
            int idx = rep * 2048 + tid * 8;
            int ki = idx >> 7, kd = idx & 127;
            *(s8v*)&K_lds[ki * 136 + kd] = kreg[rep];
            int vr = idx >> 6, vc = idx & 63;
            *(s8v*)&Vt_lds[vr * 72 + vc] = vreg[rep];
        }
        __syncthreads();
        if (kt < qt) {
            #pragma unroll
            for (int rep = 0; rep < 4; rep++) {
                int idx = rep * 2048 + tid * 8;
                int ki = idx >> 7, kd = idx & 127;
                kreg[rep] = *(const s8v*)&KT16[((size_t)(b * LL) + (kt + 1) * 64 + ki) * DD + kd];
                int vr = idx >> 6, vc = idx & 63;
                vreg[rep] = *(const s8v*)&VT16T[((size_t)b * DD + vr) * LL + (kt + 1) * 64 + vc];
            }
        }

        f4v sacc[4];
        #pragma unroll
        for (int mt = 0; mt < 4; mt++) sacc[mt] = (f4v){0.f, 0.f, 0.f, 0.f};
        #pragma unroll
        for (int c = 0; c < 4; c++) {
            #pragma unroll
            for (int mt = 0; mt < 4; mt++) {
                s8v af = *(const s8v*)&K_lds[(mt * 16 + n) * 136 + c * 32 + quad * 8];
                sacc[mt] = __builtin_amdgcn_mfma_f32_16x16x32_bf16(af, qfrag[c], sacc[mt], 0, 0, 0);
            }
        }

        bool diag = (kt == qt);
        float mloc = -INFINITY;
        #pragma unroll
        for (int mt = 0; mt < 4; mt++) {
            #pragma unroll
            for (int rr = 0; rr < 4; rr++) {
                float s = sacc[mt][rr] * SCALE;
                if (diag && (kt * 64 + mt * 16 + quad * 4 + rr) > gj) s = -INFINITY;
                sacc[mt][rr] = s;
                mloc = fmaxf(mloc, s);
            }
        }
        mloc = fmaxf(mloc, __shfl_xor(mloc, 16));
        mloc = fmaxf(mloc, __shfl_xor(mloc, 32));
        float mnew = fmaxf(m_run, mloc);
        float alpha = __expf(m_run - mnew);
        m_run = mnew;

        float rsum = 0.f;
        #pragma unroll
        for (int mt = 0; mt < 4; mt++) {
            s4v pp;
            #pragma unroll
            for (int rr = 0; rr < 4; rr++) {
                float p = __expf(sacc[mt][rr] - mnew);
                rsum += p;
                pp[rr] = (short)f2bf(p);
            }
            *(s4v*)&P_lds[(w * 16 + n) * 72 + mt * 16 + quad * 4] = pp;
        }
        rsum += __shfl_xor(rsum, 16);
        rsum += __shfl_xor(rsum, 32);
        l_run = l_run * alpha + rsum;

        #pragma unroll
        for (int rr = 0; rr < 4; rr++) {
            float a_r = __shfl(alpha, quad * 4 + rr);
            #pragma unroll
            for (int dt = 0; dt < 8; dt++) oacc[dt][rr] *= a_r;
        }

        #pragma unroll
        for (int cc = 0; cc < 2; cc++) {
            s8v pf = *(const s8v*)&P_lds[(w * 16 + n) * 72 + cc * 32 + quad * 8];
            #pragma unroll
            for (int dt = 0; dt < 8; dt++) {
                s8v vf = *(const s8v*)&Vt_lds[(dt * 16 + n) * 72 + cc * 32 + quad * 8];
                oacc[dt] = __builtin_amdgcn_mfma_f32_16x16x32_bf16(pf, vf, oacc[dt], 0, 0, 0);
            }
        }
    }

    float linv = 1.f / l_run;
    #pragma unroll
    for (int rr = 0; rr < 4; rr++) {
        float li = __shfl(linv, quad * 4 + rr);
        int t = qt * 64 + w * 16 + quad * 4 + rr;
        float* orow = BvT + ((size_t)(b * LL) + t) * DD;
        #pragma unroll
        for (int dt = 0; dt < 8; dt++)
            orow[dt * 16 + n] = oacc[dt][rr] * li;
    }
}

// ---------------- head + pred fused -----------------------------------------
__global__ __launch_bounds__(256) void head_kernel(
    const unsigned short* __restrict__ H16, const float* __restrict__ BvT,
    const unsigned short* __restrict__ emb16, const float* __restrict__ uinit,
    const int* __restrict__ qseq, const int* __restrict__ cseq,
    float* __restrict__ acc)
{
    int b = blockIdx.y;
    int t0 = blockIdx.x * 64;
    __shared__ unsigned short Btok[64 * 136];
    __shared__ unsigned short Hl[128 * 136];
    __shared__ unsigned short O_lds[64 * 136];
    int tid = threadIdx.x;
    {
        int t = tid >> 2, d0 = (tid & 3) * 32;
        const float* br = BvT + ((size_t)(b * LL) + t0 + t) * DD + d0;
        #pragma unroll
        for (int e = 0; e < 32; e += 8) {
            float4 x = *(const float4*)&br[e];
            float4 y = *(const float4*)&br[e + 4];
            s8v o;
            o[0] = (short)f2bf(x.x); o[1] = (short)f2bf(x.y);
            o[2] = (short)f2bf(x.z); o[3] = (short)f2bf(x.w);
            o[4] = (short)f2bf(y.x); o[5] = (short)f2bf(y.y);
            o[6] = (short)f2bf(y.z); o[7] = (short)f2bf(y.w);
            *(s8v*)&Btok[t * 136 + d0 + e] = o;
        }
    }
    {
        const unsigned short* src = H16 + (tid >> 1) * DD + (tid & 1) * 64;
        unsigned short* dst = &Hl[(tid >> 1) * 136 + (tid & 1) * 64];
        #pragma unroll
        for (int e = 0; e < 64; e += 8)
            *(s8v*)&dst[e] = *(const s8v*)&src[e];
    }
    __syncthreads();

    int w = tid >> 6, lane = tid & 63, n = lane & 15, quad = lane >> 4;
    f4v a2[2][4];
    #pragma unroll
    for (int mt = 0; mt < 2; mt++)
        #pragma unroll
        for (int nt = 0; nt < 4; nt++) a2[mt][nt] = (f4v){0.f, 0.f, 0.f, 0.f};
    #pragma unroll
    for (int c = 0; c < 4; c++) {
        s8v af0 = *(const s8v*)&Hl[(w * 32 + n) * 136 + c * 32 + quad * 8];
        s8v af1 = *(const s8v*)&Hl[(w * 32 + 16 + n) * 136 + c * 32 + quad * 8];
        #pragma unroll
        for (int nt = 0; nt < 4; nt++) {
            s8v bf = *(const s8v*)&Btok[(nt * 16 + n) * 136 + c * 32 + quad * 8];
            a2[0][nt] = __builtin_amdgcn_mfma_f32_16x16x32_bf16(af0, bf, a2[0][nt], 0, 0, 0);
            a2[1][nt] = __builtin_amdgcn_mfma_f32_16x16x32_bf16(af1, bf, a2[1][nt], 0, 0, 0);
        }
    }
    #pragma unroll
    for (int mt = 0; mt < 2; mt++)
        #pragma unroll
        for (int nt = 0; nt < 4; nt++) {
            int tl = nt * 16 + n;
            int r = w * 32 + mt * 16 + quad * 4;
            #pragma unroll
            for (int rr = 0; rr < 4; rr++)
                O_lds[tl * 136 + r + rr] = f2bf(a2[mt][nt][rr]);
        }
    __syncthreads();

    int g = tid >> 4, sub = tid & 15;
    float local = 0.f;
    #pragma unroll
    for (int tt = 0; tt < 4; tt++) {
        int tl = g * 4 + tt;
        int t = t0 + tl + 1;
        if (t < LL) {
            s8v uv = *(const s8v*)&O_lds[tl * 136 + sub * 8];
            int qi = qseq[b * LL + t];
            s8v ev = *(const s8v*)&emb16[(size_t)qi * DD + sub * 8];
            float s = red16(dot8bf(uv, ev));
            if (sub == 0) {
                float c = (float)cseq[b * LL + t];
                float pred = 1.f / (1.f + __expf(-s));
                local += c * __logf(pred + EPSF) + (1.f - c) * __logf(1.f - pred + EPSF);
            }
        }
    }
    if (t0 == 0 && g == 0) {
        int qi = qseq[b * LL];
        s8v ev = *(const s8v*)&emb16[(size_t)qi * DD + sub * 8];
        float4 u0 = *(const float4*)&uinit[sub * 8];
        float4 u1 = *(const float4*)&uinit[sub * 8 + 4];
        float s = u0.x * bf2f((unsigned short)ev[0]) + u0.y * bf2f((unsigned short)ev[1])
                + u0.z * bf2f((unsigned short)ev[2]) + u0.w * bf2f((unsigned short)ev[3])
                + u1.x * bf2f((unsigned short)ev[4]) + u1.y * bf2f((unsigned short)ev[5])
                + u1.z * bf2f((unsigned short)ev[6]) + u1.w * bf2f((unsigned short)ev[7]);
        s = red16(s);
        if (sub == 0) {
            float c = (float)cseq[b * LL];
            float pred = 1.f / (1.f + __expf(-s));
            local += c * __logf(pred + EPSF) + (1.f - c) * __logf(1.f - pred + EPSF);
        }
    }
    block_atomic_sum(local, acc + 2);
}

// ---------------- final combine ---------------------------------------------
__global__ void combine_kernel(
    const float* __restrict__ acc, const float* __restrict__ sd0p,
    const float* __restrict__ sd1p, const float* __restrict__ sdqp,
    float* __restrict__ out)
{
    if (threadIdx.x == 0 && blockIdx.x == 0) {
        float l0 = -acc[0], l1 = -acc[1], ls = -acc[2];
        float s0 = *sd0p, s1 = *sd1p, ss = *sdqp;
        float tf = l0 / (s0 * s0 + EPSF) + 400000.f * logf(s0 + EPSF)
                 + l1 / (s1 * s1 + EPSF) + 400000.f * logf(s1 + EPSF)
                 + ls / (ss * ss + EPSF) + 512.f * logf(ss + EPSF);
        out[0] = tf;
    }
}

extern "C" void kernel_launch(void* const* d_in, const int* in_sizes, int n_in,
                              void* d_out, int out_size, void* d_ws, size_t ws_size,
                              hipStream_t stream) {
    const float* emb   = (const float*)d_in[0];
    const float* Wrep  = (const float*)d_in[1];
    const float* Wq    = (const float*)d_in[2];
    const float* Wk    = (const float*)d_in[3];
    const float* Wv    = (const float*)d_in[4];
    const float* Hd    = (const float*)d_in[5];
    const float* uinit = (const float*)d_in[6];
    const float* sd0   = (const float*)d_in[7];
    const float* sd1   = (const float*)d_in[8];
    const float* sdq   = (const float*)d_in[9];
    const int* pe0 = (const int*)d_in[10];
    const int* ne0 = (const int*)d_in[11];
    const int* pe1 = (const int*)d_in[12];
    const int* ne1 = (const int*)d_in[13];
    const int* qs  = (const int*)d_in[14];
    const int* cs  = (const int*)d_in[15];

    const size_t SZ = (size_t)BB * LL * DD;   // 4,194,304
    char* base = (char*)d_ws;
    float* acc = (float*)base;                                  // 256 B
    unsigned short* emb16 = (unsigned short*)(base + 256);      // 12.8 MB
    unsigned short* W16   = emb16 + (size_t)NN * DD;            // 128 KB
    unsigned short* QT16  = W16 + 4 * DD * DD;
    unsigned short* KT16  = QT16 + SZ;
    unsigned short* VT16T = KT16 + SZ;                          // [b][128][512]
    float* BvT = (float*)(VT16T + SZ);                          // fp32

    hipMemsetAsync(acc, 0, 256, stream);

    cvt_emb_kernel<<<1024, 256, 0, stream>>>(emb, emb16);
    cvt_w_kernel<<<32, 256, 0, stream>>>(Wq, Wk, Wv, Hd, W16);

    edges_kernel<<<ENB, 256, 0, stream>>>(emb16, pe0, ne0, pe1, ne1, acc);

    proj_kernel<<<dim3(8, 64), 256, 0, stream>>>(emb16, Wrep, W16, qs, cs,
                                                 QT16, KT16, VT16T);
    attn_mfma_kernel<<<512, 256, 0, stream>>>(QT16, KT16, VT16T, BvT);
    head_kernel<<<dim3(8, 64), 256, 0, stream>>>(W16 + 3 * DD * DD, BvT,
                                                 emb16, uinit, qs, cs, acc);

    combine_kernel<<<1, 64, 0, stream>>>(acc, sd0, sd1, sdq, (float*)d_out);
}

// Round 7
// 206.376 us; speedup vs baseline: 1.1193x; 1.1193x over previous
//
#include <hip/hip_runtime.h>
#include <hip/hip_bf16.h>

#define EPSF 1e-8f
#define NN 50000
#define DD 128
#define BB 64
#define LL 512
#define PP0 200000
#define PP1 50000
#define SCALE 0.08838834764831845f  // 1/sqrt(128)

typedef float f4v __attribute__((ext_vector_type(4)));
typedef short s8v __attribute__((ext_vector_type(8)));
typedef short s4v __attribute__((ext_vector_type(4)));

__device__ __forceinline__ float logsigf(float x) {
    float s = 1.f / (1.f + __expf(-x));
    return __logf(s + EPSF);
}

__device__ __forceinline__ float red64(float v) {
    #pragma unroll
    for (int m = 32; m >= 1; m >>= 1) v += __shfl_xor(v, m, 64);
    return v;
}
__device__ __forceinline__ float red16(float v) {
    #pragma unroll
    for (int m = 8; m >= 1; m >>= 1) v += __shfl_xor(v, m, 64);
    return v;
}
__device__ __forceinline__ float red8(float v) {
    #pragma unroll
    for (int m = 4; m >= 1; m >>= 1) v += __shfl_xor(v, m, 64);
    return v;
}

__device__ __forceinline__ void block_atomic_sum(float local, float* dst) {
    local = red64(local);
    __shared__ float w4[4];
    if ((threadIdx.x & 63) == 0) w4[threadIdx.x >> 6] = local;
    __syncthreads();
    if (threadIdx.x == 0) atomicAdd(dst, w4[0] + w4[1] + w4[2] + w4[3]);
}

// float -> bf16 bits (round-to-nearest-even)
__device__ __forceinline__ unsigned short f2bf(float f) {
    unsigned u = __float_as_uint(f);
    unsigned r = (u + 0x7fffu + ((u >> 16) & 1u)) >> 16;
    return (unsigned short)r;
}
__device__ __forceinline__ float bf2f(unsigned short u) {
    return __uint_as_float(((unsigned)u) << 16);
}

__device__ __forceinline__ float dot8bf(s8v a, s8v b) {
    float s = 0.f;
    #pragma unroll
    for (int j = 0; j < 8; j++)
        s += bf2f((unsigned short)a[j]) * bf2f((unsigned short)b[j]);
    return s;
}

// ---------------- one-shot converts -----------------------------------------
__global__ __launch_bounds__(256) void cvt_emb_kernel(
    const float* __restrict__ emb, unsigned short* __restrict__ emb16)
{
    int stride = gridDim.x * 256 * 8;
    for (int i = (blockIdx.x * 256 + threadIdx.x) * 8; i < NN * DD; i += stride) {
        float4 a = *(const float4*)&emb[i];
        float4 b = *(const float4*)&emb[i + 4];
        s8v o;
        o[0] = (short)f2bf(a.x); o[1] = (short)f2bf(a.y);
        o[2] = (short)f2bf(a.z); o[3] = (short)f2bf(a.w);
        o[4] = (short)f2bf(b.x); o[5] = (short)f2bf(b.y);
        o[6] = (short)f2bf(b.z); o[7] = (short)f2bf(b.w);
        *(s8v*)&emb16[i] = o;
    }
}

__global__ __launch_bounds__(256) void cvt_w_kernel(
    const float* __restrict__ Wq, const float* __restrict__ Wk,
    const float* __restrict__ Wv, const float* __restrict__ Hd,
    unsigned short* __restrict__ W16)
{
    int idx = (blockIdx.x * 256 + threadIdx.x) * 8;
    int which = idx >> 14, off = idx & 16383;
    const float* src = (which == 0) ? Wq : (which == 1) ? Wk : (which == 2) ? Wv : Hd;
    float4 a = *(const float4*)&src[off];
    float4 b = *(const float4*)&src[off + 4];
    s8v o;
    o[0] = (short)f2bf(a.x); o[1] = (short)f2bf(a.y);
    o[2] = (short)f2bf(a.z); o[3] = (short)f2bf(a.w);
    o[4] = (short)f2bf(b.x); o[5] = (short)f2bf(b.y);
    o[6] = (short)f2bf(b.z); o[7] = (short)f2bf(b.w);
    *(s8v*)&W16[idx] = o;
}

// ---------------- Edge tasks: two-path, gather-count-balanced split ---------
// edge0: 800k gathers over E0B blocks; edge1: 500k gathers over E1B blocks.
// 800/E0B == 500/E1B  ->  E0B:E1B = 8:5.
#define E0B 1024
#define E1B 640
__global__ __launch_bounds__(256) void edges_kernel(
    const unsigned short* __restrict__ emb16, const int* __restrict__ pos,
    const int* __restrict__ neg, const int* __restrict__ pos1,
    const int* __restrict__ neg1, float* __restrict__ acc)
{
    if (blockIdx.x < E0B) {
        // 8 lanes per pair: 8 independent pair-chains per wave, 3-step reduce
        int sub = threadIdx.x & 7;
        int g0 = (blockIdx.x * 256 + threadIdx.x) >> 3;
        const int ng = E0B * 32;   // 32768 groups in flight
        float local = 0.f;
        for (int grp = g0; grp < 2 * PP0; grp += ng) {
            bool isneg = grp >= PP0;
            const int* e = isneg ? (neg + 2 * (grp - PP0)) : (pos + 2 * grp);
            int h = e[0], t = e[1];
            const unsigned short* hr = emb16 + (size_t)h * DD + 16 * sub;
            const unsigned short* tr = emb16 + (size_t)t * DD + 16 * sub;
            s8v a0 = *(const s8v*)&hr[0];
            s8v a1 = *(const s8v*)&hr[8];
            s8v b0 = *(const s8v*)&tr[0];
            s8v b1 = *(const s8v*)&tr[8];
            float d = red8(dot8bf(a0, b0) + dot8bf(a1, b1));
            if (sub == 0) local += logsigf(isneg ? -d : d);
        }
        block_atomic_sum(local, acc);
    } else {
        // edge1: pos pair reused x4; 10 gathers per iteration (native ILP)
        int sub = threadIdx.x & 15;
        int g0 = ((blockIdx.x - E0B) * 256 + threadIdx.x) >> 4;
        const int ng = E1B * 16;
        float local = 0.f;
        for (int i = g0; i < PP1; i += ng) {
            int ph = pos1[2 * i], pt = pos1[2 * i + 1];
            s8v vph = *(const s8v*)&emb16[(size_t)ph * DD + 8 * sub];
            s8v vpt = *(const s8v*)&emb16[(size_t)pt * DD + 8 * sub];
            float ps = red16(dot8bf(vph, vpt));
            #pragma unroll
            for (int mloop = 0; mloop < 4; mloop++) {
                int g = mloop * PP1 + i;
                int nh = neg1[2 * g], nt = neg1[2 * g + 1];
                s8v vnh = *(const s8v*)&emb16[(size_t)nh * DD + 8 * sub];
                s8v vnt = *(const s8v*)&emb16[(size_t)nt * DD + 8 * sub];
                float sh = red16(dot8bf(vnh, vpt));
                float st = red16(dot8bf(vph, vnt));
                if (sub == 0) local += logsigf(ps - sh) + logsigf(ps - st);
            }
        }
        block_atomic_sum(local, acc + 1);
    }
}

// ---------------- QKV projection, bf16 MFMA ---------------------------------
// Q,K row-major [b*L+t][d]; V written TRANSPOSED: VT16T[b][d=0..127][key=0..511]
__global__ __launch_bounds__(256) void proj_kernel(
    const unsigned short* __restrict__ emb16, const float* __restrict__ Wrep,
    const unsigned short* __restrict__ W16, const int* __restrict__ qseq,
    const int* __restrict__ cseq, unsigned short* __restrict__ QT16,
    unsigned short* __restrict__ KT16, unsigned short* __restrict__ VT16T)
{
    int b = blockIdx.y;
    int t0 = blockIdx.x * 64;
    __shared__ unsigned short Itok[64 * 136];
    __shared__ unsigned short Wl[128 * 136];   // reused as V^T[r][t] stride 72 in epilogue
    __shared__ int qs[64];
    __shared__ int cs[64];
    int tid = threadIdx.x;
    if (tid < 64) {
        qs[tid] = qseq[b * LL + t0 + tid];
        cs[tid] = cseq[b * LL + t0 + tid];
    }
    __syncthreads();
    {   // stage I[t][d] = emb[qs[t]][d] + Wrep[d][cs[t]] as bf16
        int t = tid >> 2, d0 = (tid & 3) * 32;
        const unsigned short* er = emb16 + (size_t)qs[t] * DD + d0;
        int c = cs[t];
        #pragma unroll
        for (int e = 0; e < 32; e += 8) {
            s8v raw = *(const s8v*)&er[e];
            s8v o;
            #pragma unroll
            for (int j = 0; j < 8; j++) {
                float f = bf2f((unsigned short)raw[j]) + Wrep[(d0 + e + j) * 2 + c];
                o[j] = (short)f2bf(f);
            }
            *(s8v*)&Itok[t * 136 + d0 + e] = o;
        }
    }
    int w = tid >> 6, lane = tid & 63, n = lane & 15, quad = lane >> 4;

    for (int w3 = 0; w3 < 3; w3++) {
        __syncthreads();
        {   // stage W[w3]
            const unsigned short* src = W16 + w3 * DD * DD + (tid >> 1) * DD + (tid & 1) * 64;
            unsigned short* dst = &Wl[(tid >> 1) * 136 + (tid & 1) * 64];
            #pragma unroll
            for (int e = 0; e < 64; e += 8)
                *(s8v*)&dst[e] = *(const s8v*)&src[e];
        }
        __syncthreads();
        f4v a2[2][4];
        #pragma unroll
        for (int mt = 0; mt < 2; mt++)
            #pragma unroll
            for (int nt = 0; nt < 4; nt++) a2[mt][nt] = (f4v){0.f, 0.f, 0.f, 0.f};
        #pragma unroll
        for (int c = 0; c < 4; c++) {
            s8v af0 = *(const s8v*)&Wl[(w * 32 + n) * 136 + c * 32 + quad * 8];
            s8v af1 = *(const s8v*)&Wl[(w * 32 + 16 + n) * 136 + c * 32 + quad * 8];
            #pragma unroll
            for (int nt = 0; nt < 4; nt++) {
                s8v bf = *(const s8v*)&Itok[(nt * 16 + n) * 136 + c * 32 + quad * 8];
                a2[0][nt] = __builtin_amdgcn_mfma_f32_16x16x32_bf16(af0, bf, a2[0][nt], 0, 0, 0);
                a2[1][nt] = __builtin_amdgcn_mfma_f32_16x16x32_bf16(af1, bf, a2[1][nt], 0, 0, 0);
            }
        }
        if (w3 < 2) {
            unsigned short* OUT = (w3 == 0) ? QT16 : KT16;
            #pragma unroll
            for (int mt = 0; mt < 2; mt++)
                #pragma unroll
                for (int nt = 0; nt < 4; nt++) {
                    int t = t0 + nt * 16 + n;
                    int r = w * 32 + mt * 16 + quad * 4;
                    s4v o;
                    #pragma unroll
                    for (int rr = 0; rr < 4; rr++) o[rr] = (short)f2bf(a2[mt][nt][rr]);
                    *(s4v*)&OUT[((size_t)(b * LL) + t) * DD + r] = o;
                }
        } else {
            // V: scatter into LDS [r][t] stride 72, then coalesced b128 store
            __syncthreads();   // all waves done reading Wl
            #pragma unroll
            for (int mt = 0; mt < 2; mt++)
                #pragma unroll
                for (int nt = 0; nt < 4; nt++) {
                    int tl = nt * 16 + n;
                    int r = w * 32 + mt * 16 + quad * 4;
                    #pragma unroll
                    for (int rr = 0; rr < 4; rr++)
                        Wl[(r + rr) * 72 + tl] = f2bf(a2[mt][nt][rr]);
                }
            __syncthreads();
            int row = tid >> 1, half = tid & 1;
            unsigned short* gdst = VT16T + ((size_t)b * DD + row) * LL + t0 + half * 32;
            const unsigned short* lsrc = &Wl[row * 72 + half * 32];
            #pragma unroll
            for (int e = 0; e < 32; e += 8)
                *(s8v*)&gdst[e] = *(const s8v*)&lsrc[e];
        }
    }
}

// ---------------- Flash attention, bf16 MFMA, pipelined staging -------------
__global__ __launch_bounds__(256) void attn_mfma_kernel(
    const unsigned short* __restrict__ QT16, const unsigned short* __restrict__ KT16,
    const unsigned short* __restrict__ VT16T, float* __restrict__ BvT)
{
    int id = blockIdx.x;
    int r0 = id & 255;
    int b = r0 & 63;
    int qt = (id >> 8) ? (7 - (r0 >> 6)) : (r0 >> 6);

    __shared__ unsigned short K_lds[64 * 136];   // [key][d]
    __shared__ unsigned short Vt_lds[128 * 72];  // [d][key]
    __shared__ unsigned short P_lds[64 * 72];    // [query][key]

    int tid = threadIdx.x;
    int w = tid >> 6;
    int lane = tid & 63;
    int n = lane & 15;
    int quad = lane >> 4;
    int gj = qt * 64 + w * 16 + n;

    s8v qfrag[4];
    {
        const unsigned short* qrow = QT16 + ((size_t)(b * LL) + gj) * DD;
        #pragma unroll
        for (int c = 0; c < 4; c++)
            qfrag[c] = *(const s8v*)&qrow[c * 32 + quad * 8];
    }

    f4v oacc[8];
    #pragma unroll
    for (int dt = 0; dt < 8; dt++) oacc[dt] = (f4v){0.f, 0.f, 0.f, 0.f};
    float m_run = -INFINITY, l_run = 0.f;

    s8v kreg[4], vreg[4];
    #pragma unroll
    for (int rep = 0; rep < 4; rep++) {
        int idx = rep * 2048 + tid * 8;
        int ki = idx >> 7, kd = idx & 127;
        kreg[rep] = *(const s8v*)&KT16[((size_t)(b * LL) + ki) * DD + kd];
        int vr = idx >> 6, vc = idx & 63;
        vreg[rep] = *(const s8v*)&VT16T[((size_t)b * DD + vr) * LL + vc];
    }

    for (int kt = 0; kt <= qt; ++kt) {
        __syncthreads();
        #pragma unroll
        for (int rep = 0; rep < 4; rep++) {
            int idx = rep * 2048 + tid * 8;
            int ki = idx >> 7, kd = idx & 127;
            *(s8v*)&K_lds[ki * 136 + kd] = kreg[rep];
            int vr = idx >> 6, vc = idx & 63;
            *(s8v*)&Vt_lds[vr * 72 + vc] = vreg[rep];
        }
        __syncthreads();
        if (kt < qt) {
            #pragma unroll
            for (int rep = 0; rep < 4; rep++) {
                int idx = rep * 2048 + tid * 8;
                int ki = idx >> 7, kd = idx & 127;
                kreg[rep] = *(const s8v*)&KT16[((size_t)(b * LL) + (kt + 1) * 64 + ki) * DD + kd];
                int vr = idx >> 6, vc = idx & 63;
                vreg[rep] = *(const s8v*)&VT16T[((size_t)b * DD + vr) * LL + (kt + 1) * 64 + vc];
            }
        }

        f4v sacc[4];
        #pragma unroll
        for (int mt = 0; mt < 4; mt++) sacc[mt] = (f4v){0.f, 0.f, 0.f, 0.f};
        #pragma unroll
        for (int c = 0; c < 4; c++) {
            #pragma unroll
            for (int mt = 0; mt < 4; mt++) {
                s8v af = *(const s8v*)&K_lds[(mt * 16 + n) * 136 + c * 32 + quad * 8];
                sacc[mt] = __builtin_amdgcn_mfma_f32_16x16x32_bf16(af, qfrag[c], sacc[mt], 0, 0, 0);
            }
        }

        bool diag = (kt == qt);
        float mloc = -INFINITY;
        #pragma unroll
        for (int mt = 0; mt < 4; mt++) {
            #pragma unroll
            for (int rr = 0; rr < 4; rr++) {
                float s = sacc[mt][rr] * SCALE;
                if (diag && (kt * 64 + mt * 16 + quad * 4 + rr) > gj) s = -INFINITY;
                sacc[mt][rr] = s;
                mloc = fmaxf(mloc, s);
            }
        }
        mloc = fmaxf(mloc, __shfl_xor(mloc, 16));
        mloc = fmaxf(mloc, __shfl_xor(mloc, 32));
        float mnew = fmaxf(m_run, mloc);
        float alpha = __expf(m_run - mnew);
        m_run = mnew;

        float rsum = 0.f;
        #pragma unroll
        for (int mt = 0; mt < 4; mt++) {
            s4v pp;
            #pragma unroll
            for (int rr = 0; rr < 4; rr++) {
                float p = __expf(sacc[mt][rr] - mnew);
                rsum += p;
                pp[rr] = (short)f2bf(p);
            }
            *(s4v*)&P_lds[(w * 16 + n) * 72 + mt * 16 + quad * 4] = pp;
        }
        rsum += __shfl_xor(rsum, 16);
        rsum += __shfl_xor(rsum, 32);
        l_run = l_run * alpha + rsum;

        #pragma unroll
        for (int rr = 0; rr < 4; rr++) {
            float a_r = __shfl(alpha, quad * 4 + rr);
            #pragma unroll
            for (int dt = 0; dt < 8; dt++) oacc[dt][rr] *= a_r;
        }

        #pragma unroll
        for (int cc = 0; cc < 2; cc++) {
            s8v pf = *(const s8v*)&P_lds[(w * 16 + n) * 72 + cc * 32 + quad * 8];
            #pragma unroll
            for (int dt = 0; dt < 8; dt++) {
                s8v vf = *(const s8v*)&Vt_lds[(dt * 16 + n) * 72 + cc * 32 + quad * 8];
                oacc[dt] = __builtin_amdgcn_mfma_f32_16x16x32_bf16(pf, vf, oacc[dt], 0, 0, 0);
            }
        }
    }

    float linv = 1.f / l_run;
    #pragma unroll
    for (int rr = 0; rr < 4; rr++) {
        float li = __shfl(linv, quad * 4 + rr);
        int t = qt * 64 + w * 16 + quad * 4 + rr;
        float* orow = BvT + ((size_t)(b * LL) + t) * DD;
        #pragma unroll
        for (int dt = 0; dt < 8; dt++)
            orow[dt * 16 + n] = oacc[dt][rr] * li;
    }
}

// ---------------- head + pred fused -----------------------------------------
__global__ __launch_bounds__(256) void head_kernel(
    const unsigned short* __restrict__ H16, const float* __restrict__ BvT,
    const unsigned short* __restrict__ emb16, const float* __restrict__ uinit,
    const int* __restrict__ qseq, const int* __restrict__ cseq,
    float* __restrict__ acc)
{
    int b = blockIdx.y;
    int t0 = blockIdx.x * 64;
    __shared__ unsigned short Btok[64 * 136];
    __shared__ unsigned short Hl[128 * 136];
    __shared__ unsigned short O_lds[64 * 136];
    int tid = threadIdx.x;
    {
        int t = tid >> 2, d0 = (tid & 3) * 32;
        const float* br = BvT + ((size_t)(b * LL) + t0 + t) * DD + d0;
        #pragma unroll
        for (int e = 0; e < 32; e += 8) {
            float4 x = *(const float4*)&br[e];
            float4 y = *(const float4*)&br[e + 4];
            s8v o;
            o[0] = (short)f2bf(x.x); o[1] = (short)f2bf(x.y);
            o[2] = (short)f2bf(x.z); o[3] = (short)f2bf(x.w);
            o[4] = (short)f2bf(y.x); o[5] = (short)f2bf(y.y);
            o[6] = (short)f2bf(y.z); o[7] = (short)f2bf(y.w);
            *(s8v*)&Btok[t * 136 + d0 + e] = o;
        }
    }
    {
        const unsigned short* src = H16 + (tid >> 1) * DD + (tid & 1) * 64;
        unsigned short* dst = &Hl[(tid >> 1) * 136 + (tid & 1) * 64];
        #pragma unroll
        for (int e = 0; e < 64; e += 8)
            *(s8v*)&dst[e] = *(const s8v*)&src[e];
    }
    __syncthreads();

    int w = tid >> 6, lane = tid & 63, n = lane & 15, quad = lane >> 4;
    f4v a2[2][4];
    #pragma unroll
    for (int mt = 0; mt < 2; mt++)
        #pragma unroll
        for (int nt = 0; nt < 4; nt++) a2[mt][nt] = (f4v){0.f, 0.f, 0.f, 0.f};
    #pragma unroll
    for (int c = 0; c < 4; c++) {
        s8v af0 = *(const s8v*)&Hl[(w * 32 + n) * 136 + c * 32 + quad * 8];
        s8v af1 = *(const s8v*)&Hl[(w * 32 + 16 + n) * 136 + c * 32 + quad * 8];
        #pragma unroll
        for (int nt = 0; nt < 4; nt++) {
            s8v bf = *(const s8v*)&Btok[(nt * 16 + n) * 136 + c * 32 + quad * 8];
            a2[0][nt] = __builtin_amdgcn_mfma_f32_16x16x32_bf16(af0, bf, a2[0][nt], 0, 0, 0);
            a2[1][nt] = __builtin_amdgcn_mfma_f32_16x16x32_bf16(af1, bf, a2[1][nt], 0, 0, 0);
        }
    }
    #pragma unroll
    for (int mt = 0; mt < 2; mt++)
        #pragma unroll
        for (int nt = 0; nt < 4; nt++) {
            int tl = nt * 16 + n;
            int r = w * 32 + mt * 16 + quad * 4;
            #pragma unroll
            for (int rr = 0; rr < 4; rr++)
                O_lds[tl * 136 + r + rr] = f2bf(a2[mt][nt][rr]);
        }
    __syncthreads();

    int g = tid >> 4, sub = tid & 15;
    float local = 0.f;
    #pragma unroll
    for (int tt = 0; tt < 4; tt++) {
        int tl = g * 4 + tt;
        int t = t0 + tl + 1;
        if (t < LL) {
            s8v uv = *(const s8v*)&O_lds[tl * 136 + sub * 8];
            int qi = qseq[b * LL + t];
            s8v ev = *(const s8v*)&emb16[(size_t)qi * DD + sub * 8];
            float s = red16(dot8bf(uv, ev));
            if (sub == 0) {
                float c = (float)cseq[b * LL + t];
                float pred = 1.f / (1.f + __expf(-s));
                local += c * __logf(pred + EPSF) + (1.f - c) * __logf(1.f - pred + EPSF);
            }
        }
    }
    if (t0 == 0 && g == 0) {
        int qi = qseq[b * LL];
        s8v ev = *(const s8v*)&emb16[(size_t)qi * DD + sub * 8];
        float4 u0 = *(const float4*)&uinit[sub * 8];
        float4 u1 = *(const float4*)&uinit[sub * 8 + 4];
        float s = u0.x * bf2f((unsigned short)ev[0]) + u0.y * bf2f((unsigned short)ev[1])
                + u0.z * bf2f((unsigned short)ev[2]) + u0.w * bf2f((unsigned short)ev[3])
                + u1.x * bf2f((unsigned short)ev[4]) + u1.y * bf2f((unsigned short)ev[5])
                + u1.z * bf2f((unsigned short)ev[6]) + u1.w * bf2f((unsigned short)ev[7]);
        s = red16(s);
        if (sub == 0) {
            float c = (float)cseq[b * LL];
            float pred = 1.f / (1.f + __expf(-s));
            local += c * __logf(pred + EPSF) + (1.f - c) * __logf(1.f - pred + EPSF);
        }
    }
    block_atomic_sum(local, acc + 2);
}

// ---------------- final combine ---------------------------------------------
__global__ void combine_kernel(
    const float* __restrict__ acc, const float* __restrict__ sd0p,
    const float* __restrict__ sd1p, const float* __restrict__ sdqp,
    float* __restrict__ out)
{
    if (threadIdx.x == 0 && blockIdx.x == 0) {
        float l0 = -acc[0], l1 = -acc[1], ls = -acc[2];
        float s0 = *sd0p, s1 = *sd1p, ss = *sdqp;
        float tf = l0 / (s0 * s0 + EPSF) + 400000.f * logf(s0 + EPSF)
                 + l1 / (s1 * s1 + EPSF) + 400000.f * logf(s1 + EPSF)
                 + ls / (ss * ss + EPSF) + 512.f * logf(ss + EPSF);
        out[0] = tf;
    }
}

extern "C" void kernel_launch(void* const* d_in, const int* in_sizes, int n_in,
                              void* d_out, int out_size, void* d_ws, size_t ws_size,
                              hipStream_t stream) {
    const float* emb   = (const float*)d_in[0];
    const float* Wrep  = (const float*)d_in[1];
    const float* Wq    = (const float*)d_in[2];
    const float* Wk    = (const float*)d_in[3];
    const float* Wv    = (const float*)d_in[4];
    const float* Hd    = (const float*)d_in[5];
    const float* uinit = (const float*)d_in[6];
    const float* sd0   = (const float*)d_in[7];
    const float* sd1   = (const float*)d_in[8];
    const float* sdq   = (const float*)d_in[9];
    const int* pe0 = (const int*)d_in[10];
    const int* ne0 = (const int*)d_in[11];
    const int* pe1 = (const int*)d_in[12];
    const int* ne1 = (const int*)d_in[13];
    const int* qs  = (const int*)d_in[14];
    const int* cs  = (const int*)d_in[15];

    const size_t SZ = (size_t)BB * LL * DD;   // 4,194,304
    char* base = (char*)d_ws;
    float* acc = (float*)base;                                  // 256 B
    unsigned short* emb16 = (unsigned short*)(base + 256);      // 12.8 MB
    unsigned short* W16   = emb16 + (size_t)NN * DD;            // 128 KB
    unsigned short* QT16  = W16 + 4 * DD * DD;
    unsigned short* KT16  = QT16 + SZ;
    unsigned short* VT16T = KT16 + SZ;                          // [b][128][512]
    float* BvT = (float*)(VT16T + SZ);                          // fp32

    hipMemsetAsync(acc, 0, 256, stream);

    cvt_emb_kernel<<<1024, 256, 0, stream>>>(emb, emb16);
    cvt_w_kernel<<<32, 256, 0, stream>>>(Wq, Wk, Wv, Hd, W16);

    edges_kernel<<<E0B + E1B, 256, 0, stream>>>(emb16, pe0, ne0, pe1, ne1, acc);

    proj_kernel<<<dim3(8, 64), 256, 0, stream>>>(emb16, Wrep, W16, qs, cs,
                                                 QT16, KT16, VT16T);
    attn_mfma_kernel<<<512, 256, 0, stream>>>(QT16, KT16, VT16T, BvT);
    head_kernel<<<dim3(8, 64), 256, 0, stream>>>(W16 + 3 * DD * DD, BvT,
                                                 emb16, uinit, qs, cs, acc);

    combine_kernel<<<1, 64, 0, stream>>>(acc, sd0, sd1, sdq, (float*)d_out);
}